// Round 3
// baseline (365.964 us; speedup 1.0000x reference)
//
#include <hip/hip_runtime.h>
#include <hip/hip_bf16.h>

// Problem constants (from reference): B=2, S=2048, D=1024, H=16, DH=64
#define BB 2
#define SS 2048
#define DDIM 1024
#define HH 16
#define DH 64

typedef __attribute__((ext_vector_type(8))) short bf16x8;
typedef __attribute__((ext_vector_type(4))) short s16x4;
typedef __attribute__((ext_vector_type(4))) float f32x4;

__device__ __forceinline__ short f2bf(float f) {
  unsigned u = __builtin_bit_cast(unsigned, f);
  unsigned r = (u + 0x7fffu + ((u >> 16) & 1u)) >> 16;
  return (short)r;
}

__device__ __forceinline__ f32x4 mfma16(bf16x8 a, bf16x8 b, f32x4 c) {
  return __builtin_amdgcn_mfma_f32_16x16x32_bf16(a, b, c, 0, 0, 0);
}

// ---------------------------------------------------------------------------
// GEMM: C[M][N] = A[M][K](fp32) * W[K][N](fp32) + bias, C = bf16 or fp32.
// 128x128 tile, BK=32, 4 waves (2x2), each wave 64x64 via 4x4 MFMA frags.
// fp32->bf16 conversion fused into LDS staging; W transposed into LDS so
// both A and B fragments are contiguous-K ds_read_b128.
// LDS stride 40 elems (80B): 16B-aligned rows, 2-way bank aliasing max.
// ---------------------------------------------------------------------------
struct GB { const float* A; const float* W; const float* bias; void* C; };
struct GB3 { GB g[3]; };

template<int OUT_F32>
__global__ __launch_bounds__(256) void gemm_k(GB3 gbs, int M, int N, int K) {
  __shared__ short As[128][40];   // [m][k]
  __shared__ short Bs[128][40];   // [n][k]  (W transposed during staging)
  const GB gb = gbs.g[blockIdx.z];
  const int tid = threadIdx.x;
  const int lane = tid & 63, wave = tid >> 6;
  const int wr = (wave >> 1) * 64, wc = (wave & 1) * 64;
  const int g = lane >> 4, r = lane & 15;
  const int bm = blockIdx.x * 128, bn = blockIdx.y * 128;
  f32x4 acc[4][4] = {};

  for (int k0 = 0; k0 < K; k0 += 32) {
    // ---- stage A tile (128x32 fp32 -> bf16) ----
    {
      const float* Af = gb.A;
      #pragma unroll
      for (int it = 0; it < 4; ++it) {
        int row = it * 32 + (tid >> 3);
        int kc = (tid & 7) * 4;
        float4 v = *(const float4*)(Af + (size_t)(bm + row) * K + k0 + kc);
        s16x4 t;
        t[0] = f2bf(v.x); t[1] = f2bf(v.y); t[2] = f2bf(v.z); t[3] = f2bf(v.w);
        *(s16x4*)&As[row][kc] = t;
      }
    }
    // ---- stage B tile (32x128 fp32 -> bf16, transposed to [n][k]) ----
    {
      const float* W = gb.W;
      #pragma unroll
      for (int p = 0; p < 4; ++p) {
        int kk = p * 8 + (tid >> 5);
        int nc = (tid & 31) * 4;
        float4 v = *(const float4*)(W + (size_t)(k0 + kk) * N + bn + nc);
        Bs[nc + 0][kk] = f2bf(v.x);
        Bs[nc + 1][kk] = f2bf(v.y);
        Bs[nc + 2][kk] = f2bf(v.z);
        Bs[nc + 3][kk] = f2bf(v.w);
      }
    }
    __syncthreads();
    bf16x8 af[4], bfr[4];
    #pragma unroll
    for (int m = 0; m < 4; ++m) af[m] = *(const bf16x8*)&As[wr + m * 16 + r][g * 8];
    #pragma unroll
    for (int n = 0; n < 4; ++n) bfr[n] = *(const bf16x8*)&Bs[wc + n * 16 + r][g * 8];
    #pragma unroll
    for (int m = 0; m < 4; ++m)
      #pragma unroll
      for (int n = 0; n < 4; ++n)
        acc[m][n] = mfma16(af[m], bfr[n], acc[m][n]);
    __syncthreads();
  }

  // ---- epilogue: C row = (lane>>4)*4 + i, col = lane&15 (m89-verified) ----
  #pragma unroll
  for (int m = 0; m < 4; ++m)
    #pragma unroll
    for (int n = 0; n < 4; ++n) {
      int col = bn + wc + n * 16 + r;
      float bv = gb.bias[col];
      #pragma unroll
      for (int i = 0; i < 4; ++i) {
        int row = bm + wr + m * 16 + g * 4 + i;
        float val = acc[m][n][i] + bv;
        if (OUT_F32) ((float*)gb.C)[(size_t)row * N + col] = val;
        else         ((short*)gb.C)[(size_t)row * N + col] = f2bf(val);
      }
    }
}

// ---------------------------------------------------------------------------
// Flash attention (causal). Q,K,V bf16 [B*S][H*DH]; ctx fp32 same layout.
// Block: 256 thr (4 waves), 128 q-rows/block (32/wave). KV tile = 64.
// Wave computes S(32x64) = Q K^T via MFMA, online softmax with 16-lane-group
// shfl reductions, P->LDS bf16, PV via MFMA with V transposed in LDS.
// ---------------------------------------------------------------------------
__global__ __launch_bounds__(256) void attn_k(const short* __restrict__ Q,
                                              const short* __restrict__ Km,
                                              const short* __restrict__ Vm,
                                              float* __restrict__ ctx) {
  __shared__ short Vt[64][72];        // [dh][kv]  (144B rows: aligned, 2-way banks)
  __shared__ short Pl[4][32][72];     // per-wave P [qrow][kv]
  const int tid = threadIdx.x;
  const int lane = tid & 63, w = tid >> 6;
  const int g = lane >> 4, r = lane & 15;
  const int b = blockIdx.z, h = blockIdx.y;
  const int qt0 = blockIdx.x * 128;
  const int qr0 = qt0 + w * 32;

  // Q fragments (A-operand): row = lane&15, k = (lane>>4)*8 + j
  bf16x8 qa[2][2];
  #pragma unroll
  for (int m = 0; m < 2; ++m)
    #pragma unroll
    for (int kc = 0; kc < 2; ++kc)
      qa[m][kc] = *(const bf16x8*)(Q + ((size_t)b * SS + qr0 + m * 16 + r) * DDIM
                                     + h * DH + kc * 32 + g * 8);

  f32x4 o[2][4] = {};
  float mrun[2][4], lrun[2][4];
  #pragma unroll
  for (int m = 0; m < 2; ++m)
    #pragma unroll
    for (int i = 0; i < 4; ++i) { mrun[m][i] = -3.0e38f; lrun[m][i] = 0.f; }

  const int nt = (qt0 + 128) / 64;
  for (int t = 0; t < nt; ++t) {
    const int kv0 = t * 64;
    __syncthreads();  // protect Vt from previous-iteration readers
    // ---- stage V tile transposed: Vt[dh][kv] ----
    {
      int kv = tid >> 2;
      int dhc = (tid & 3) * 16;
      const short* src = Vm + ((size_t)b * SS + kv0 + kv) * DDIM + h * DH + dhc;
      bf16x8 v0 = *(const bf16x8*)(src);
      bf16x8 v1 = *(const bf16x8*)(src + 8);
      #pragma unroll
      for (int j = 0; j < 8; ++j) Vt[dhc + j][kv] = v0[j];
      #pragma unroll
      for (int j = 0; j < 8; ++j) Vt[dhc + 8 + j][kv] = v1[j];
    }
    __syncthreads();

    if (kv0 <= qr0 + 31) {   // wave has at least one unmasked row in this tile
      // ---- S = Q K^T ----
      f32x4 sf[2][4];
      #pragma unroll
      for (int n = 0; n < 4; ++n) {
        const short* kp = Km + ((size_t)b * SS + kv0 + n * 16 + r) * DDIM + h * DH;
        bf16x8 kb0 = *(const bf16x8*)(kp + g * 8);
        bf16x8 kb1 = *(const bf16x8*)(kp + 32 + g * 8);
        #pragma unroll
        for (int m = 0; m < 2; ++m) {
          f32x4 z = {0.f, 0.f, 0.f, 0.f};
          f32x4 s0 = mfma16(qa[m][0], kb0, z);
          sf[m][n] = mfma16(qa[m][1], kb1, s0);
        }
      }
      // ---- online softmax (rows g*4+i of rowblock m; cols across 16-lane group) ----
      #pragma unroll
      for (int m = 0; m < 2; ++m) {
        const int qrow = qr0 + m * 16 + g * 4;
        float mn[4], al[4], rs[4];
        #pragma unroll
        for (int i = 0; i < 4; ++i) {
          float mx = -3.0e38f;
          #pragma unroll
          for (int n = 0; n < 4; ++n) {
            float v = sf[m][n][i] * 0.125f;               // 1/sqrt(64)
            if (kv0 + n * 16 + r > qrow + i) v = -1.0e38f; // causal mask
            sf[m][n][i] = v;
            mx = fmaxf(mx, v);
          }
          #pragma unroll
          for (int off = 1; off < 16; off <<= 1) mx = fmaxf(mx, __shfl_xor(mx, off));
          mn[i] = fmaxf(mrun[m][i], mx);
          al[i] = __expf(mrun[m][i] - mn[i]);
          mrun[m][i] = mn[i];
          rs[i] = 0.f;
        }
        #pragma unroll
        for (int n = 0; n < 4; ++n)
          #pragma unroll
          for (int i = 0; i < 4; ++i) {
            float p = __expf(sf[m][n][i] - mn[i]);
            rs[i] += p;
            Pl[w][m * 16 + g * 4 + i][n * 16 + r] = f2bf(p);
          }
        #pragma unroll
        for (int i = 0; i < 4; ++i) {
          float rsum = rs[i];
          #pragma unroll
          for (int off = 1; off < 16; off <<= 1) rsum += __shfl_xor(rsum, off);
          lrun[m][i] = lrun[m][i] * al[i] + rsum;
          #pragma unroll
          for (int n = 0; n < 4; ++n) o[m][n][i] *= al[i];
        }
      }
      // ---- O += P V ----
      #pragma unroll
      for (int kc = 0; kc < 2; ++kc) {
        bf16x8 pa0 = *(const bf16x8*)&Pl[w][r][kc * 32 + g * 8];
        bf16x8 pa1 = *(const bf16x8*)&Pl[w][16 + r][kc * 32 + g * 8];
        #pragma unroll
        for (int n = 0; n < 4; ++n) {
          bf16x8 vb = *(const bf16x8*)&Vt[n * 16 + r][kc * 32 + g * 8];
          o[0][n] = mfma16(pa0, vb, o[0][n]);
          o[1][n] = mfma16(pa1, vb, o[1][n]);
        }
      }
    }
  }

  // ---- finalize: ctx = O / l (fp32 out to protect final GEMM accuracy) ----
  #pragma unroll
  for (int m = 0; m < 2; ++m)
    #pragma unroll
    for (int n = 0; n < 4; ++n)
      #pragma unroll
      for (int i = 0; i < 4; ++i) {
        int row = qr0 + m * 16 + g * 4 + i;
        float val = o[m][n][i] / lrun[m][i];
        ctx[((size_t)b * SS + row) * (HH * DH) + h * DH + n * 16 + r] = val;
      }
}

// ---------------------------------------------------------------------------
extern "C" void kernel_launch(void* const* d_in, const int* in_sizes, int n_in,
                              void* d_out, int out_size, void* d_ws, size_t ws_size,
                              hipStream_t stream) {
  const float* queries = (const float*)d_in[0];
  const float* keys    = (const float*)d_in[1];
  const float* values  = (const float*)d_in[2];
  // d_in[3] = mask: deterministic causal triu(k=1) — handled analytically
  const float* Wq = (const float*)d_in[4];
  const float* bq = (const float*)d_in[5];
  const float* Wk = (const float*)d_in[6];
  const float* bk = (const float*)d_in[7];
  const float* Wv = (const float*)d_in[8];
  const float* bv = (const float*)d_in[9];
  const float* Wo = (const float*)d_in[10];
  const float* bo = (const float*)d_in[11];

  char* ws = (char*)d_ws;
  short* Qb  = (short*)(ws);                 //  8.39 MB bf16 [4096][1024]
  short* Kb  = (short*)(ws + 8388608);       //  8.39 MB
  short* Vb  = (short*)(ws + 16777216);      //  8.39 MB
  float* ctx = (float*)(ws + 25165824);      // 16.78 MB fp32 [4096][1024]

  const int M = BB * SS, N = HH * DH, K = DDIM;

  GB3 g1;
  g1.g[0] = { queries, Wq, bq, (void*)Qb };
  g1.g[1] = { keys,    Wk, bk, (void*)Kb };
  g1.g[2] = { values,  Wv, bv, (void*)Vb };
  hipLaunchKernelGGL((gemm_k<0>), dim3(M / 128, N / 128, 3), dim3(256), 0, stream,
                     g1, M, N, K);

  hipLaunchKernelGGL(attn_k, dim3(SS / 128, HH, BB), dim3(256), 0, stream,
                     Qb, Kb, Vb, ctx);

  GB3 g3;
  g3.g[0] = { ctx, Wo, bo, d_out };
  g3.g[1] = g3.g[0];
  g3.g[2] = g3.g[0];
  hipLaunchKernelGGL((gemm_k<1>), dim3(M / 128, (DDIM) / 128, 1), dim3(256), 0, stream,
                     g3, M, DDIM, K);
}

// Round 4
// 263.107 us; speedup vs baseline: 1.3909x; 1.3909x over previous
//
#include <hip/hip_runtime.h>
#include <hip/hip_bf16.h>

// Problem constants (from reference): B=2, S=2048, D=1024, H=16, DH=64
#define BB 2
#define SS 2048
#define DDIM 1024
#define HH 16
#define DH 64

typedef __attribute__((ext_vector_type(8))) short bf16x8;
typedef __attribute__((ext_vector_type(4))) short s16x4;
typedef __attribute__((ext_vector_type(4))) float f32x4;

__device__ __forceinline__ short f2bf(float f) {
  unsigned u = __builtin_bit_cast(unsigned, f);
  unsigned r = (u + 0x7fffu + ((u >> 16) & 1u)) >> 16;
  return (short)r;
}

__device__ __forceinline__ f32x4 mfma16(bf16x8 a, bf16x8 b, f32x4 c) {
  return __builtin_amdgcn_mfma_f32_16x16x32_bf16(a, b, c, 0, 0, 0);
}

// async global->LDS, 16B/lane, wave-uniform LDS base + lane*16 linear dest
__device__ __forceinline__ void gload16(const short* g, short* l) {
  __builtin_amdgcn_global_load_lds(
      (const __attribute__((address_space(1))) void*)g,
      (__attribute__((address_space(3))) void*)l, 16, 0, 0);
}

// ---------------------------------------------------------------------------
// W transpose+convert: Wt[n][k] = bf16(W[k][n]), 1024x1024, 4 matrices (z).
// 64x64 tiles via LDS. Tiny one-shot kernel (~8 MB total).
// ---------------------------------------------------------------------------
struct TW { const float* W; short* Wt; };
struct TW4 { TW t[4]; };

__global__ __launch_bounds__(256) void transw_k(TW4 ts) {
  __shared__ short tile[64][72];
  const TW tw = ts.t[blockIdx.z];
  const int k0 = blockIdx.x * 64, n0 = blockIdx.y * 64;
  const int tr = threadIdx.x >> 4, tc4 = (threadIdx.x & 15) * 4;
  #pragma unroll
  for (int it = 0; it < 4; ++it) {
    int k = k0 + tr + it * 16;
    float4 v = *(const float4*)(tw.W + (size_t)k * 1024 + n0 + tc4);
    tile[tc4 + 0][tr + it * 16] = f2bf(v.x);
    tile[tc4 + 1][tr + it * 16] = f2bf(v.y);
    tile[tc4 + 2][tr + it * 16] = f2bf(v.z);
    tile[tc4 + 3][tr + it * 16] = f2bf(v.w);
  }
  __syncthreads();
  #pragma unroll
  for (int it = 0; it < 4; ++it) {
    int n = n0 + tr + it * 16;
    s16x4 o;
    o[0] = tile[tr + it * 16][tc4 + 0];
    o[1] = tile[tr + it * 16][tc4 + 1];
    o[2] = tile[tr + it * 16][tc4 + 2];
    o[3] = tile[tr + it * 16][tc4 + 3];
    *(s16x4*)(tw.Wt + (size_t)n * 1024 + k0 + tc4) = o;
  }
}

// ---------------------------------------------------------------------------
// GEMM: C[M][N] = A[M][K] * Wt[N][K]^T + bias.
// A_F32: A fp32, converted to bf16 during LDS staging (float4 + f2bf).
// else:  A bf16, staged via global_load_lds (2 instr/wave, zero VALU).
// B always bf16 pre-transposed, staged via global_load_lds.
// 128x128 tile, BK=32, 4 waves (2x2), 4x4 16x16x32 MFMA frags/wave.
// LDS linear [128][32] (64B rows): frag ds_read_b128 worst 2-way bank alias.
// ---------------------------------------------------------------------------
struct GB { const void* A; const short* Bt; const float* bias; void* C; };
struct GB3 { GB g[3]; };

template<int A_F32, int OUT_F32>
__global__ __launch_bounds__(256) void gemm_k(GB3 gbs, int M, int N, int K) {
  __shared__ short As[128 * 32];
  __shared__ short Bs[128 * 32];
  const GB gb = gbs.g[blockIdx.z];
  const int tid = threadIdx.x;
  const int lane = tid & 63, wave = tid >> 6;
  const int wr = (wave >> 1) * 64, wc = (wave & 1) * 64;
  const int g = lane >> 4, r = lane & 15;
  const int bm = blockIdx.x * 128, bn = blockIdx.y * 128;
  const int arow = lane >> 2, acol = (lane & 3) * 8;  // gload lane mapping
  f32x4 acc[4][4] = {};

  for (int k0 = 0; k0 < K; k0 += 32) {
    if (A_F32) {
      const float* Af = (const float*)gb.A;
      #pragma unroll
      for (int it = 0; it < 4; ++it) {
        int row = it * 32 + (tid >> 3);
        int kc = (tid & 7) * 4;
        float4 v = *(const float4*)(Af + (size_t)(bm + row) * K + k0 + kc);
        s16x4 t;
        t[0] = f2bf(v.x); t[1] = f2bf(v.y); t[2] = f2bf(v.z); t[3] = f2bf(v.w);
        *(s16x4*)&As[row * 32 + kc] = t;
      }
    } else {
      const short* Ab = (const short*)gb.A;
      #pragma unroll
      for (int s = 0; s < 2; ++s) {
        int rowc = wave * 32 + s * 16;
        gload16(Ab + (size_t)(bm + rowc + arow) * K + k0 + acol, &As[rowc * 32]);
      }
    }
    {
      #pragma unroll
      for (int s = 0; s < 2; ++s) {
        int rowc = wave * 32 + s * 16;
        gload16(gb.Bt + (size_t)(bn + rowc + arow) * K + k0 + acol, &Bs[rowc * 32]);
      }
    }
    __syncthreads();
    bf16x8 af[4], bfr[4];
    #pragma unroll
    for (int m = 0; m < 4; ++m) af[m] = *(const bf16x8*)&As[(wr + m * 16 + r) * 32 + g * 8];
    #pragma unroll
    for (int n = 0; n < 4; ++n) bfr[n] = *(const bf16x8*)&Bs[(wc + n * 16 + r) * 32 + g * 8];
    #pragma unroll
    for (int m = 0; m < 4; ++m)
      #pragma unroll
      for (int n = 0; n < 4; ++n)
        acc[m][n] = mfma16(af[m], bfr[n], acc[m][n]);
    __syncthreads();
  }

  // ---- epilogue: C row = (lane>>4)*4 + i, col = lane&15 (m89-verified) ----
  #pragma unroll
  for (int m = 0; m < 4; ++m)
    #pragma unroll
    for (int n = 0; n < 4; ++n) {
      int col = bn + wc + n * 16 + r;
      float bv = gb.bias[col];
      #pragma unroll
      for (int i = 0; i < 4; ++i) {
        int row = bm + wr + m * 16 + g * 4 + i;
        float val = acc[m][n][i] + bv;
        if (OUT_F32) ((float*)gb.C)[(size_t)row * N + col] = val;
        else         ((short*)gb.C)[(size_t)row * N + col] = f2bf(val);
      }
    }
}

// ---------------------------------------------------------------------------
// Flash attention (causal). Q,K,V bf16 [B*S][H*DH]; ctx bf16 same layout.
// Block: 128 thr (2 waves), 64 q-rows/block (32/wave). KV tile = 64.
// grid.x reversed (longest-first LPT); 1024 blocks, 18.4 KB LDS ->
// whole grid co-resident (~8 blocks/CU cap) for latency hiding.
// Wave inner algorithm identical to the verified round-0 baseline.
// ---------------------------------------------------------------------------
__global__ __launch_bounds__(128) void attn_k(const short* __restrict__ Q,
                                              const short* __restrict__ Km,
                                              const short* __restrict__ Vm,
                                              short* __restrict__ ctx) {
  __shared__ short Vt[64][72];        // [dh][kv]
  __shared__ short Pl[2][32][72];     // per-wave P [qrow][kv]
  const int tid = threadIdx.x;
  const int lane = tid & 63, w = tid >> 6;
  const int g = lane >> 4, r = lane & 15;
  const int b = blockIdx.z, h = blockIdx.y;
  const int qt0 = (gridDim.x - 1 - blockIdx.x) * 64;   // longest-first
  const int qr0 = qt0 + w * 32;

  // Q fragments (A-operand): row = lane&15, k = (lane>>4)*8 + j
  bf16x8 qa[2][2];
  #pragma unroll
  for (int m = 0; m < 2; ++m)
    #pragma unroll
    for (int kc = 0; kc < 2; ++kc)
      qa[m][kc] = *(const bf16x8*)(Q + ((size_t)b * SS + qr0 + m * 16 + r) * DDIM
                                     + h * DH + kc * 32 + g * 8);

  f32x4 o[2][4] = {};
  float mrun[2][4], lrun[2][4];
  #pragma unroll
  for (int m = 0; m < 2; ++m)
    #pragma unroll
    for (int i = 0; i < 4; ++i) { mrun[m][i] = -3.0e38f; lrun[m][i] = 0.f; }

  const int nt = qt0 / 64 + 1;
  for (int t = 0; t < nt; ++t) {
    const int kv0 = t * 64;
    __syncthreads();  // protect Vt from previous-iteration readers
    // ---- stage V tile transposed: Vt[dh][kv] ----
    {
      int kv = tid >> 1;
      int dhc = (tid & 1) * 32;
      const short* src = Vm + ((size_t)b * SS + kv0 + kv) * DDIM + h * DH + dhc;
      bf16x8 v0 = *(const bf16x8*)(src);
      bf16x8 v1 = *(const bf16x8*)(src + 8);
      bf16x8 v2 = *(const bf16x8*)(src + 16);
      bf16x8 v3 = *(const bf16x8*)(src + 24);
      #pragma unroll
      for (int j = 0; j < 8; ++j) Vt[dhc + j][kv] = v0[j];
      #pragma unroll
      for (int j = 0; j < 8; ++j) Vt[dhc + 8 + j][kv] = v1[j];
      #pragma unroll
      for (int j = 0; j < 8; ++j) Vt[dhc + 16 + j][kv] = v2[j];
      #pragma unroll
      for (int j = 0; j < 8; ++j) Vt[dhc + 24 + j][kv] = v3[j];
    }
    __syncthreads();

    // ---- S = Q K^T ----
    f32x4 sf[2][4];
    #pragma unroll
    for (int n = 0; n < 4; ++n) {
      const short* kp = Km + ((size_t)b * SS + kv0 + n * 16 + r) * DDIM + h * DH;
      bf16x8 kb0 = *(const bf16x8*)(kp + g * 8);
      bf16x8 kb1 = *(const bf16x8*)(kp + 32 + g * 8);
      #pragma unroll
      for (int m = 0; m < 2; ++m) {
        f32x4 z = {0.f, 0.f, 0.f, 0.f};
        f32x4 s0 = mfma16(qa[m][0], kb0, z);
        sf[m][n] = mfma16(qa[m][1], kb1, s0);
      }
    }
    // ---- online softmax ----
    #pragma unroll
    for (int m = 0; m < 2; ++m) {
      const int qrow = qr0 + m * 16 + g * 4;
      float mn[4], al[4], rs[4];
      #pragma unroll
      for (int i = 0; i < 4; ++i) {
        float mx = -3.0e38f;
        #pragma unroll
        for (int n = 0; n < 4; ++n) {
          float v = sf[m][n][i] * 0.125f;               // 1/sqrt(64)
          if (kv0 + n * 16 + r > qrow + i) v = -1.0e38f; // causal mask
          sf[m][n][i] = v;
          mx = fmaxf(mx, v);
        }
        #pragma unroll
        for (int off = 1; off < 16; off <<= 1) mx = fmaxf(mx, __shfl_xor(mx, off));
        mn[i] = fmaxf(mrun[m][i], mx);
        al[i] = __expf(mrun[m][i] - mn[i]);
        mrun[m][i] = mn[i];
        rs[i] = 0.f;
      }
      #pragma unroll
      for (int n = 0; n < 4; ++n)
        #pragma unroll
        for (int i = 0; i < 4; ++i) {
          float p = __expf(sf[m][n][i] - mn[i]);
          rs[i] += p;
          Pl[w][m * 16 + g * 4 + i][n * 16 + r] = f2bf(p);
        }
      #pragma unroll
      for (int i = 0; i < 4; ++i) {
        float rsum = rs[i];
        #pragma unroll
        for (int off = 1; off < 16; off <<= 1) rsum += __shfl_xor(rsum, off);
        lrun[m][i] = lrun[m][i] * al[i] + rsum;
        #pragma unroll
        for (int n = 0; n < 4; ++n) o[m][n][i] *= al[i];
      }
    }
    // ---- O += P V ----
    #pragma unroll
    for (int kc = 0; kc < 2; ++kc) {
      bf16x8 pa0 = *(const bf16x8*)&Pl[w][r][kc * 32 + g * 8];
      bf16x8 pa1 = *(const bf16x8*)&Pl[w][16 + r][kc * 32 + g * 8];
      #pragma unroll
      for (int n = 0; n < 4; ++n) {
        bf16x8 vb = *(const bf16x8*)&Vt[n * 16 + r][kc * 32 + g * 8];
        o[0][n] = mfma16(pa0, vb, o[0][n]);
        o[1][n] = mfma16(pa1, vb, o[1][n]);
      }
    }
  }

  // ---- finalize: ctx = bf16(O / l) ----
  #pragma unroll
  for (int m = 0; m < 2; ++m)
    #pragma unroll
    for (int n = 0; n < 4; ++n)
      #pragma unroll
      for (int i = 0; i < 4; ++i) {
        int row = qr0 + m * 16 + g * 4 + i;
        float val = o[m][n][i] / lrun[m][i];
        ctx[((size_t)b * SS + row) * (HH * DH) + h * DH + n * 16 + r] = f2bf(val);
      }
}

// ---------------------------------------------------------------------------
extern "C" void kernel_launch(void* const* d_in, const int* in_sizes, int n_in,
                              void* d_out, int out_size, void* d_ws, size_t ws_size,
                              hipStream_t stream) {
  const float* queries = (const float*)d_in[0];
  const float* keys    = (const float*)d_in[1];
  const float* values  = (const float*)d_in[2];
  // d_in[3] = mask: deterministic causal triu(k=1) — handled analytically
  const float* Wq = (const float*)d_in[4];
  const float* bq = (const float*)d_in[5];
  const float* Wk = (const float*)d_in[6];
  const float* bk = (const float*)d_in[7];
  const float* Wv = (const float*)d_in[8];
  const float* bv = (const float*)d_in[9];
  const float* Wo = (const float*)d_in[10];
  const float* bo = (const float*)d_in[11];

  char* ws = (char*)d_ws;                     // 40 MiB total (proven size)
  short* Qb  = (short*)(ws);                  //  8.39 MB bf16 [4096][1024]
  short* Kb  = (short*)(ws +  8388608);       //  8.39 MB
  short* Vb  = (short*)(ws + 16777216);       //  8.39 MB
  short* ctx = (short*)(ws + 25165824);       //  8.39 MB bf16 [4096][1024]
  short* WqT = (short*)(ws + 33554432);       //  2 MB bf16 [1024][1024]
  short* WkT = (short*)(ws + 35651584);
  short* WvT = (short*)(ws + 37748736);
  short* WoT = (short*)(ws + 39845888);

  const int M = BB * SS, N = HH * DH, K = DDIM;

  TW4 tw;
  tw.t[0] = { Wq, WqT };
  tw.t[1] = { Wk, WkT };
  tw.t[2] = { Wv, WvT };
  tw.t[3] = { Wo, WoT };
  hipLaunchKernelGGL(transw_k, dim3(16, 16, 4), dim3(256), 0, stream, tw);

  GB3 g1;
  g1.g[0] = { queries, WqT, bq, (void*)Qb };
  g1.g[1] = { keys,    WkT, bk, (void*)Kb };
  g1.g[2] = { values,  WvT, bv, (void*)Vb };
  hipLaunchKernelGGL((gemm_k<1, 0>), dim3(M / 128, N / 128, 3), dim3(256), 0, stream,
                     g1, M, N, K);

  hipLaunchKernelGGL(attn_k, dim3(SS / 64, HH, BB), dim3(128), 0, stream,
                     Qb, Kb, Vb, ctx);

  GB3 g3;
  g3.g[0] = { ctx, WoT, bo, d_out };
  g3.g[1] = g3.g[0];
  g3.g[2] = g3.g[0];
  hipLaunchKernelGGL((gemm_k<0, 1>), dim3(M / 128, DDIM / 128, 1), dim3(256), 0, stream,
                     g3, M, DDIM, K);
}